// Round 2
// baseline (18461.873 us; speedup 1.0000x reference)
//
#include <hip/hip_runtime.h>
#include <hip/hip_cooperative_groups.h>

namespace cg = cooperative_groups;

#define BB 64      // batch
#define TT 256     // time
#define EE 256     // embed dim
#define NU 1024    // hidden units
#define N3 3072    // 3*NU

static __device__ __forceinline__ const float* uniform_ptr(const float* p) {
    uint64_t v = (uint64_t)(uintptr_t)p;
    uint32_t lo = __builtin_amdgcn_readfirstlane((uint32_t)v);
    uint32_t hi = __builtin_amdgcn_readfirstlane((uint32_t)(v >> 32));
    return (const float*)(uintptr_t)(((uint64_t)hi << 32) | lo);
}

// ---------------------------------------------------------------------------
// Kernel 0: pack U[k][g*NU+u] -> Upack[u*3+g][k]  (so each scan wave's 6
// columns are 6 contiguous-in-k streams at stride NU)
// ---------------------------------------------------------------------------
__global__ __launch_bounds__(256) void upack_kernel(
    const float* __restrict__ U, float* __restrict__ up)
{
    __shared__ float t32[32][33];
    const int c0 = blockIdx.x * 32, k0 = blockIdx.y * 32;
    const int tx = threadIdx.x & 31, ty = threadIdx.x >> 5;   // ty < 8
    #pragma unroll
    for (int i = 0; i < 4; ++i) {
        int k = ty + i * 8;
        t32[k][tx] = U[(size_t)(k0 + k) * N3 + c0 + tx];
    }
    __syncthreads();
    #pragma unroll
    for (int i = 0; i < 4; ++i) {
        int cl = ty + i * 8;
        int c = c0 + cl;
        int u = c & 1023, g = c >> 10;
        up[(size_t)(u * 3 + g) * NU + k0 + tx] = t32[tx][cl];
    }
}

// ---------------------------------------------------------------------------
// Kernel 1: xproj[t*B+b][n] = emb[x[b,t]] @ W + b0   (M=16384,K=256,N=3072)
// 128x128 tile, 8x8 micro-tile, K-chunks of 32.
// ---------------------------------------------------------------------------
__global__ __launch_bounds__(256) void xproj_kernel(
    const int* __restrict__ x, const float* __restrict__ emb,
    const float* __restrict__ W, const float* __restrict__ bias,
    float* __restrict__ xp)
{
    __shared__ float AsT[32][132];   // [k][m]
    __shared__ float Ws[32][132];    // [k][n]
    __shared__ int toks[128];

    const int tid = threadIdx.x;
    const int mt = blockIdx.x / 24, nt = blockIdx.x % 24;
    const int m0 = mt * 128, n0 = nt * 128;

    if (tid < 128) {
        int mg = m0 + tid;                       // m = t*64 + b
        toks[tid] = x[(mg & 63) * TT + (mg >> 6)];
    }
    __syncthreads();

    const int tx = tid & 15, ty = tid >> 4;
    float acc[8][8] = {};

    for (int kb = 0; kb < 8; ++kb) {
        const int k0 = kb * 32;
        if (kb) __syncthreads();
        #pragma unroll
        for (int i = 0; i < 4; ++i) {
            int idx = tid + 256 * i;
            int m = idx >> 3, c4 = idx & 7;
            float4 av = *(const float4*)(emb + (size_t)toks[m] * EE + k0 + c4 * 4);
            AsT[c4 * 4 + 0][m] = av.x; AsT[c4 * 4 + 1][m] = av.y;
            AsT[c4 * 4 + 2][m] = av.z; AsT[c4 * 4 + 3][m] = av.w;
            int r = idx >> 5, w4 = idx & 31;
            *(float4*)&Ws[r][w4 * 4] =
                *(const float4*)(W + (size_t)(k0 + r) * N3 + n0 + w4 * 4);
        }
        __syncthreads();
        #pragma unroll 8
        for (int kk = 0; kk < 32; ++kk) {
            float a8[8], w8[8];
            *(float4*)a8       = *(const float4*)&AsT[kk][ty * 8];
            *(float4*)(a8 + 4) = *(const float4*)&AsT[kk][ty * 8 + 4];
            *(float4*)w8       = *(const float4*)&Ws[kk][tx * 8];
            *(float4*)(w8 + 4) = *(const float4*)&Ws[kk][tx * 8 + 4];
            #pragma unroll
            for (int i = 0; i < 8; ++i)
                #pragma unroll
                for (int j = 0; j < 8; ++j) acc[i][j] += a8[i] * w8[j];
        }
    }

    float b8[8];
    *(float4*)b8       = *(const float4*)(bias + n0 + tx * 8);
    *(float4*)(b8 + 4) = *(const float4*)(bias + n0 + tx * 8 + 4);
    #pragma unroll
    for (int i = 0; i < 8; ++i) {
        size_t ro = (size_t)(m0 + ty * 8 + i) * N3 + n0 + tx * 8;
        float4 o0, o1;
        o0.x = acc[i][0] + b8[0]; o0.y = acc[i][1] + b8[1];
        o0.z = acc[i][2] + b8[2]; o0.w = acc[i][3] + b8[3];
        o1.x = acc[i][4] + b8[4]; o1.y = acc[i][5] + b8[5];
        o1.z = acc[i][6] + b8[6]; o1.w = acc[i][7] + b8[7];
        *(float4*)(xp + ro)     = o0;
        *(float4*)(xp + ro + 4) = o1;
    }
}

// ---------------------------------------------------------------------------
// Kernel 2: persistent cooperative GRU scan. 256 blocks x 512 threads.
// Block owns 4 units (12 columns). Wave w = (q = w>>1 k-quarter, half = w&1
// column-half of 6 cols). lane = batch. U via scalar loads (SGPR), h via
// direct global b128 loads (L1/L2-hot). LDS only for 4-way k reduction.
// ---------------------------------------------------------------------------
__global__ __launch_bounds__(512) void gru_scan(
    const int* __restrict__ xtok, const float* __restrict__ hidden,
    const float* __restrict__ upack, const float* __restrict__ bias,
    const float* __restrict__ xproj, float* __restrict__ out,
    float* h0, float* h1)
{
    __shared__ float red[8][6][64];   // 12 KB

    const int tid = threadIdx.x;
    const int bid = blockIdx.x;
    const int u0 = bid * 4;
    const int w = __builtin_amdgcn_readfirstlane(tid >> 6);
    const int q = w >> 1, half = w & 1;
    const int lane = tid & 63;                 // batch for GEMM
    const int gb = tid >> 2, gj = tid & 3;     // gating mapping (tid < 256)

    float* state_out = out + (size_t)BB * TT * NU;

    // 6 u-streams: cols = units {u0+half*2, u0+half*2+1} x gates {0,1,2},
    // stream s at up + s*NU, k-range quarter q.
    const float* up = uniform_ptr(upack + (size_t)(u0 + half * 2) * 3 * NU + q * 256);

    float brz = 0.f, brr = 0.f, brh = 0.f;
    if (tid < 256) {
        brz = bias[N3 + 0 * NU + u0 + gj];
        brr = bias[N3 + 1 * NU + u0 + gj];
        brh = bias[N3 + 2 * NU + u0 + gj];
        h0[(size_t)gb * NU + u0 + gj] = hidden[(size_t)gb * NU + u0 + gj];
    }

    cg::grid_group grid = cg::this_grid();

    const float* hc = h0;
    float* hn = h1;

    for (int t = 0; t < TT; ++t) {
        grid.sync();

        // prefetch gate inputs early (consumed ~6000 cyc later)
        float xz = 0.f, xr = 0.f, xh = 0.f, hold = 0.f;
        int tok = 1;
        if (tid < 256) {
            size_t xb = ((size_t)t * BB + gb) * N3 + u0 + gj;
            xz = xproj[xb];
            xr = xproj[xb + NU];
            xh = xproj[xb + 2 * NU];
            tok = xtok[gb * TT + t];
            hold = hc[(size_t)gb * NU + u0 + gj];
        }

        // ---- recurrent GEMM: acc[s] = sum_k h[lane][k] * Upack[s][k] ----
        float acc[6] = {0.f, 0.f, 0.f, 0.f, 0.f, 0.f};
        const float* hrow = hc + (size_t)lane * NU + q * 256;

        float uA[6][4], uB[6][4], hA[4], hB[4];
        *(float4*)hA = *(const float4*)(hrow);
        #pragma unroll
        for (int s = 0; s < 6; ++s)
            *(float4*)uA[s] = *(const float4*)(up + s * NU);

        for (int c = 0; c < 64; c += 2) {
            const int k1 = (c + 1) * 4;
            *(float4*)hB = *(const float4*)(hrow + k1);
            #pragma unroll
            for (int s = 0; s < 6; ++s)
                *(float4*)uB[s] = *(const float4*)(up + s * NU + k1);
            #pragma unroll
            for (int s = 0; s < 6; ++s)
                #pragma unroll
                for (int kk = 0; kk < 4; ++kk) acc[s] += uA[s][kk] * hA[kk];
            if (c + 2 < 64) {
                const int k2 = (c + 2) * 4;
                *(float4*)hA = *(const float4*)(hrow + k2);
                #pragma unroll
                for (int s = 0; s < 6; ++s)
                    *(float4*)uA[s] = *(const float4*)(up + s * NU + k2);
            }
            #pragma unroll
            for (int s = 0; s < 6; ++s)
                #pragma unroll
                for (int kk = 0; kk < 4; ++kk) acc[s] += uB[s][kk] * hB[kk];
        }

        #pragma unroll
        for (int s = 0; s < 6; ++s) red[w][s][lane] = acc[s];
        __syncthreads();

        // ---- gating: thread (gb, gj) finishes unit u0+gj, batch gb ----
        if (tid < 256) {
            const int hj = gj >> 1, ju = gj & 1;
            float rz = red[0 + hj][ju * 3 + 0][gb] + red[2 + hj][ju * 3 + 0][gb]
                     + red[4 + hj][ju * 3 + 0][gb] + red[6 + hj][ju * 3 + 0][gb] + brz;
            float rr = red[0 + hj][ju * 3 + 1][gb] + red[2 + hj][ju * 3 + 1][gb]
                     + red[4 + hj][ju * 3 + 1][gb] + red[6 + hj][ju * 3 + 1][gb] + brr;
            float rh = red[0 + hj][ju * 3 + 2][gb] + red[2 + hj][ju * 3 + 2][gb]
                     + red[4 + hj][ju * 3 + 2][gb] + red[6 + hj][ju * 3 + 2][gb] + brh;

            float z  = 1.f / (1.f + expf(-(xz + rz)));
            float r  = 1.f / (1.f + expf(-(xr + rr)));
            float hh = tanhf(xh + r * rh);
            float hnew = z * hold + (1.f - z) * hh;
            if (tok == 0) hnew = hold;   // mask_zero: carry state through

            hn[(size_t)gb * NU + u0 + gj] = hnew;
            out[((size_t)gb * TT + t) * NU + u0 + gj] = hnew;
            if (t == TT - 1) state_out[(size_t)gb * NU + u0 + gj] = hnew;
        }

        const float* tmp = hc; hc = hn; hn = (float*)tmp;
    }
}

// ---------------------------------------------------------------------------
extern "C" void kernel_launch(void* const* d_in, const int* in_sizes, int n_in,
                              void* d_out, int out_size, void* d_ws, size_t ws_size,
                              hipStream_t stream) {
    const int*   x      = (const int*)d_in[0];
    const float* hidden = (const float*)d_in[1];
    const float* emb    = (const float*)d_in[2];
    const float* W      = (const float*)d_in[3];
    const float* U      = (const float*)d_in[4];
    const float* bvec   = (const float*)d_in[5];

    float* out = (float*)d_out;

    float* xproj = (float*)d_ws;                          // 50,331,648 floats
    float* upack = xproj + (size_t)16384 * N3;            //  3,145,728 floats
    float* h0    = upack + (size_t)3 * NU * NU;           //     65,536 floats
    float* h1    = h0 + (size_t)BB * NU;                  //     65,536 floats

    upack_kernel<<<dim3(96, 32), dim3(256), 0, stream>>>(U, upack);
    xproj_kernel<<<dim3(3072), dim3(256), 0, stream>>>(x, emb, W, bvec, xproj);

    void* args[] = {(void*)&x, (void*)&hidden, (void*)&upack, (void*)&bvec,
                    (void*)&xproj, (void*)&out, (void*)&h0, (void*)&h1};
    hipLaunchCooperativeKernel((const void*)gru_scan, dim3(256), dim3(512),
                               args, 0, stream);
}

// Round 3
// 8282.829 us; speedup vs baseline: 2.2289x; 2.2289x over previous
//
#include <hip/hip_runtime.h>

#define BB 64      // batch
#define TT 256     // time
#define EE 256     // embed dim
#define NU 1024    // hidden units
#define N3 3072    // 3*NU

// ---------------------------------------------------------------------------
// Kernel 0a: pack U[k][g*NU+u] -> Upack[u*3+g][k]
// ---------------------------------------------------------------------------
__global__ __launch_bounds__(256) void upack_kernel(
    const float* __restrict__ U, float* __restrict__ up)
{
    __shared__ float t32[32][33];
    const int c0 = blockIdx.x * 32, k0 = blockIdx.y * 32;
    const int tx = threadIdx.x & 31, ty = threadIdx.x >> 5;   // ty < 8
    #pragma unroll
    for (int i = 0; i < 4; ++i) {
        int k = ty + i * 8;
        t32[k][tx] = U[(size_t)(k0 + k) * N3 + c0 + tx];
    }
    __syncthreads();
    #pragma unroll
    for (int i = 0; i < 4; ++i) {
        int cl = ty + i * 8;
        int c = c0 + cl;
        int u = c & 1023, g = c >> 10;
        up[(size_t)(u * 3 + g) * NU + k0 + tx] = t32[tx][cl];
    }
}

// ---------------------------------------------------------------------------
// Kernel 0b: transpose tokens x[b][t] -> xT[t][b]
// ---------------------------------------------------------------------------
__global__ __launch_bounds__(64) void tokT_kernel(
    const int* __restrict__ x, int* __restrict__ xT)
{
    const int t = blockIdx.x, b = threadIdx.x;
    xT[t * BB + b] = x[b * TT + t];
}

// ---------------------------------------------------------------------------
// Kernel 0c: init hT[u][b] = hidden[b][u]
// ---------------------------------------------------------------------------
__global__ __launch_bounds__(256) void hinit_kernel(
    const float* __restrict__ hidden, float* __restrict__ hT)
{
    const int u = blockIdx.x * 4 + (threadIdx.x >> 6);
    const int b = threadIdx.x & 63;
    hT[u * BB + b] = hidden[(size_t)b * NU + u];
}

// ---------------------------------------------------------------------------
// Kernel 1: xprojT[t][c][b] = (emb[x[b,t]] @ W + b0)[c]   transposed store
// M=16384 (t*64+b), K=256, N=3072. 128x128 tile, 8x8 micro-tile.
// ---------------------------------------------------------------------------
__global__ __launch_bounds__(256) void xprojT_kernel(
    const int* __restrict__ x, const float* __restrict__ emb,
    const float* __restrict__ W, const float* __restrict__ bias,
    float* __restrict__ xpT)
{
    __shared__ float AsT[32][132];   // [k][m]
    __shared__ float Ws[32][132];    // [k][n]
    __shared__ int toks[128];

    const int tid = threadIdx.x;
    const int mt = blockIdx.x / 24, nt = blockIdx.x % 24;
    const int m0 = mt * 128, n0 = nt * 128;

    if (tid < 128) {
        int mg = m0 + tid;                       // m = t*64 + b
        toks[tid] = x[(mg & 63) * TT + (mg >> 6)];
    }
    __syncthreads();

    const int tx = tid & 15, ty = tid >> 4;
    float acc[8][8] = {};

    for (int kb = 0; kb < 8; ++kb) {
        const int k0 = kb * 32;
        if (kb) __syncthreads();
        #pragma unroll
        for (int i = 0; i < 4; ++i) {
            int idx = tid + 256 * i;
            int m = idx >> 3, c4 = idx & 7;
            float4 av = *(const float4*)(emb + (size_t)toks[m] * EE + k0 + c4 * 4);
            AsT[c4 * 4 + 0][m] = av.x; AsT[c4 * 4 + 1][m] = av.y;
            AsT[c4 * 4 + 2][m] = av.z; AsT[c4 * 4 + 3][m] = av.w;
            int r = idx >> 5, w4 = idx & 31;
            *(float4*)&Ws[r][w4 * 4] =
                *(const float4*)(W + (size_t)(k0 + r) * N3 + n0 + w4 * 4);
        }
        __syncthreads();
        #pragma unroll 8
        for (int kk = 0; kk < 32; ++kk) {
            float a8[8], w8[8];
            *(float4*)a8       = *(const float4*)&AsT[kk][ty * 8];
            *(float4*)(a8 + 4) = *(const float4*)&AsT[kk][ty * 8 + 4];
            *(float4*)w8       = *(const float4*)&Ws[kk][tx * 8];
            *(float4*)(w8 + 4) = *(const float4*)&Ws[kk][tx * 8 + 4];
            #pragma unroll
            for (int i = 0; i < 8; ++i)
                #pragma unroll
                for (int j = 0; j < 8; ++j) acc[i][j] += a8[i] * w8[j];
        }
    }

    // transposed store: xpT[t][c][b], thread covers 8 consecutive b for 1 t
    float b8[8];
    *(float4*)b8       = *(const float4*)(bias + n0 + tx * 8);
    *(float4*)(b8 + 4) = *(const float4*)(bias + n0 + tx * 8 + 4);
    const int t0 = mt * 2 + (ty >> 3);
    const int bb0 = (ty & 7) * 8;
    #pragma unroll
    for (int j = 0; j < 8; ++j) {
        const int c = n0 + tx * 8 + j;
        float4 lo, hi;
        lo.x = acc[0][j] + b8[j]; lo.y = acc[1][j] + b8[j];
        lo.z = acc[2][j] + b8[j]; lo.w = acc[3][j] + b8[j];
        hi.x = acc[4][j] + b8[j]; hi.y = acc[5][j] + b8[j];
        hi.z = acc[6][j] + b8[j]; hi.w = acc[7][j] + b8[j];
        size_t base = ((size_t)t0 * N3 + c) * BB + bb0;
        *(float4*)(xpT + base)     = lo;
        *(float4*)(xpT + base + 4) = hi;
    }
}

// ---------------------------------------------------------------------------
// Kernel 2: one GRU timestep. 256 blocks x 512 threads; block owns units
// [u0,u0+4) = 12 columns. Wave w: q=w>>1 (k-quarter), half=w&1 (2-unit half).
// lane = batch. hT[k][b] coalesced; U slice L2-resident (same block -> same
// slice every step). Kernel boundary = device-wide barrier (no coop sync).
// ---------------------------------------------------------------------------
__global__ __launch_bounds__(512) void gru_step(
    const int t,
    const int* __restrict__ xT, const float* __restrict__ upack,
    const float* __restrict__ bias, const float* __restrict__ xpT,
    float* __restrict__ out,
    const float* __restrict__ hc, float* __restrict__ hn)
{
    __shared__ float red[8][6][64];   // 12 KB

    const int tid = threadIdx.x;
    const int u0 = blockIdx.x * 4;
    const int w = tid >> 6;
    const int q = w >> 1, half = w & 1;
    const int lane = tid & 63;

    // ---- prefetch gate inputs (waves 0-3: j = unit idx, b = lane) ----
    float xz = 0.f, xr = 0.f, xh = 0.f, hold = 0.f, brz = 0.f, brr = 0.f, brh = 0.f;
    int tok = 1;
    const int j = w;            // for tid < 256: unit offset
    const int b = lane;
    if (tid < 256) {
        size_t xb = ((size_t)t * N3 + u0 + j) * BB + b;
        xz = xpT[xb];
        xr = xpT[xb + (size_t)NU * BB];
        xh = xpT[xb + (size_t)2 * NU * BB];
        tok = xT[t * BB + b];
        hold = hc[(u0 + j) * BB + b];
        brz = bias[N3 + 0 * NU + u0 + j];
        brr = bias[N3 + 1 * NU + u0 + j];
        brh = bias[N3 + 2 * NU + u0 + j];
    }

    // ---- recurrent GEMM: acc[s] = sum_k hT[k][lane] * Upack[s][k] ----
    // streams s = du*3+g for units {u0+half*2+du}, k in quarter q
    const float* up = upack + (size_t)(u0 + half * 2) * 3 * NU + q * 256;
    const float* hq = hc + q * 256 * BB;

    float acc[6] = {0.f, 0.f, 0.f, 0.f, 0.f, 0.f};
    #pragma unroll 4
    for (int c = 0; c < 64; ++c) {
        float u4[6][4];
        #pragma unroll
        for (int s = 0; s < 6; ++s)
            *(float4*)u4[s] = *(const float4*)(up + s * NU + c * 4);
        float hv[4];
        #pragma unroll
        for (int kk = 0; kk < 4; ++kk)
            hv[kk] = hq[(c * 4 + kk) * BB + lane];
        #pragma unroll
        for (int s = 0; s < 6; ++s)
            #pragma unroll
            for (int kk = 0; kk < 4; ++kk)
                acc[s] += u4[s][kk] * hv[kk];
    }

    #pragma unroll
    for (int s = 0; s < 6; ++s) red[w][s][lane] = acc[s];
    __syncthreads();

    // ---- gating: thread (j = tid>>6, b = tid&63), tid < 256 ----
    if (tid < 256) {
        const int h2 = j >> 1, du = j & 1;
        float rz = red[0 + h2][du * 3 + 0][b] + red[2 + h2][du * 3 + 0][b]
                 + red[4 + h2][du * 3 + 0][b] + red[6 + h2][du * 3 + 0][b] + brz;
        float rr = red[0 + h2][du * 3 + 1][b] + red[2 + h2][du * 3 + 1][b]
                 + red[4 + h2][du * 3 + 1][b] + red[6 + h2][du * 3 + 1][b] + brr;
        float rh = red[0 + h2][du * 3 + 2][b] + red[2 + h2][du * 3 + 2][b]
                 + red[4 + h2][du * 3 + 2][b] + red[6 + h2][du * 3 + 2][b] + brh;

        float z  = 1.f / (1.f + expf(-(xz + rz)));
        float r  = 1.f / (1.f + expf(-(xr + rr)));
        float hh = tanhf(xh + r * rh);
        float hnew = z * hold + (1.f - z) * hh;
        if (tok == 0) hnew = hold;   // mask_zero: carry state

        hn[(u0 + j) * BB + b] = hnew;
        out[((size_t)b * TT + t) * NU + u0 + j] = hnew;
        if (t == TT - 1) {
            float* state_out = out + (size_t)BB * TT * NU;
            state_out[(size_t)b * NU + u0 + j] = hnew;
        }
    }
}

// ---------------------------------------------------------------------------
extern "C" void kernel_launch(void* const* d_in, const int* in_sizes, int n_in,
                              void* d_out, int out_size, void* d_ws, size_t ws_size,
                              hipStream_t stream) {
    const int*   x      = (const int*)d_in[0];
    const float* hidden = (const float*)d_in[1];
    const float* emb    = (const float*)d_in[2];
    const float* W      = (const float*)d_in[3];
    const float* U      = (const float*)d_in[4];
    const float* bvec   = (const float*)d_in[5];

    float* out = (float*)d_out;

    float* xpT   = (float*)d_ws;                          // 50,331,648 floats
    float* upack = xpT + (size_t)16384 * N3;              //  3,145,728 floats
    float* h0    = upack + (size_t)3 * NU * NU;           //     65,536 floats
    float* h1    = h0 + (size_t)NU * BB;                  //     65,536 floats
    int*   xT    = (int*)(h1 + (size_t)NU * BB);          //     16,384 ints

    upack_kernel<<<dim3(96, 32), dim3(256), 0, stream>>>(U, upack);
    tokT_kernel<<<dim3(TT), dim3(64), 0, stream>>>(x, xT);
    hinit_kernel<<<dim3(256), dim3(256), 0, stream>>>(hidden, h0);
    xprojT_kernel<<<dim3(3072), dim3(256), 0, stream>>>(x, emb, W, bvec, xpT);

    float* hc = h0;
    float* hn = h1;
    for (int t = 0; t < TT; ++t) {
        gru_step<<<dim3(256), dim3(512), 0, stream>>>(
            t, xT, upack, bvec, xpT, out, hc, hn);
        float* tmp = hc; hc = hn; hn = tmp;
    }
}